// Round 1
// baseline (241.896 us; speedup 1.0000x reference)
//
#include <hip/hip_runtime.h>
#include <hip/hip_bf16.h>

#define S_LEN 2048
#define NHEADS 32
#define NKV 8
#define GQ 4
#define HD 128
#define QK_SCALE 0.08838834764831845f   // 1/sqrt(128)
#define LOG2E 1.4426950408889634f

#define BQ 64                 // q rows per block
#define BK 32                 // kv rows per tile
#define NQT (S_LEN / BQ)      // 32 q tiles

#define K_STRIDE 136          // padded LDS row stride (shorts) for K tile
#define VT_STRIDE 40          // padded LDS row stride (shorts) for V^T tile
#define P_STRIDE 40           // padded LDS row stride (shorts) for P tile

typedef __attribute__((ext_vector_type(8))) short bf16x8;
typedef __attribute__((ext_vector_type(4))) float f32x4;

__device__ inline short f2bf(float f) {
    // round-to-nearest-even fp32 -> bf16 (inputs are finite)
    unsigned u = __float_as_uint(f);
    u += 0x7fffu + ((u >> 16) & 1u);
    return (short)(u >> 16);
}

__global__ __launch_bounds__(256) void attn_fwd(
    const float* __restrict__ Q, const float* __restrict__ K,
    const float* __restrict__ V, const float* __restrict__ SL,
    float* __restrict__ O)
{
    const int bx   = blockIdx.x;
    const int h    = bx & (NHEADS - 1);          // head
    const int qt   = (NQT - 1) - (bx / NHEADS);  // heavy tiles dispatch first
    const int kvh  = h >> 2;                     // h / GQ
    const float slope = SL[h];

    const int tid  = threadIdx.x;
    const int w    = tid >> 6;        // wave 0..3
    const int lane = tid & 63;
    const int l16  = lane & 15;
    const int lq   = lane >> 4;       // 0..3

    __shared__ short Ks[BK * K_STRIDE];        // K tile, row-major [k][d]
    __shared__ short VTs[HD * VT_STRIDE];      // V tile transposed [d][k]
    __shared__ short Ps[4][16 * P_STRIDE];     // per-wave P tile [q][k]

    const int qrow0 = qt * BQ + w * 16;        // this wave's first q row

    // ---- preload Q fragments (A-operand: row = l16, k = 8*lq + i) ----
    bf16x8 qf[4];
    {
        const float* qp = Q + (size_t)(qrow0 + l16) * (NHEADS * HD) + h * HD + lq * 8;
        #pragma unroll
        for (int d0 = 0; d0 < 4; ++d0) {
            f32x4 a = *(const f32x4*)(qp + d0 * 32);
            f32x4 b = *(const f32x4*)(qp + d0 * 32 + 4);
            bf16x8 f;
            f[0] = f2bf(a[0]); f[1] = f2bf(a[1]); f[2] = f2bf(a[2]); f[3] = f2bf(a[3]);
            f[4] = f2bf(b[0]); f[5] = f2bf(b[1]); f[6] = f2bf(b[2]); f[7] = f2bf(b[3]);
            qf[d0] = f;
        }
    }

    f32x4 acc[8];
    #pragma unroll
    for (int t = 0; t < 8; ++t) acc[t] = (f32x4){0.f, 0.f, 0.f, 0.f};
    float m_i[4] = {-1e30f, -1e30f, -1e30f, -1e30f};
    float l_i[4] = {0.f, 0.f, 0.f, 0.f};

    const int kv_end = qt * BQ + BQ;   // causal: only tiles with kb < qrow_max+1

    for (int kb = 0; kb < kv_end; kb += BK) {
        __syncthreads();   // previous tile's LDS reads complete

        // ---- stage K tile: 32 x 128, coalesced global, b128 LDS writes ----
        #pragma unroll
        for (int c0 = 0; c0 < 2; ++c0) {
            int c = tid + c0 * 256;
            int r = c >> 4, cc = c & 15;
            const float* kp = K + (size_t)(kb + r) * (NKV * HD) + kvh * HD + cc * 8;
            f32x4 a = *(const f32x4*)(kp);
            f32x4 b = *(const f32x4*)(kp + 4);
            bf16x8 f;
            f[0] = f2bf(a[0]); f[1] = f2bf(a[1]); f[2] = f2bf(a[2]); f[3] = f2bf(a[3]);
            f[4] = f2bf(b[0]); f[5] = f2bf(b[1]); f[6] = f2bf(b[2]); f[7] = f2bf(b[3]);
            *(bf16x8*)(&Ks[r * K_STRIDE + cc * 8]) = f;
        }
        // ---- stage V^T tile: [d][k], scalar scatter writes (fix later) ----
        #pragma unroll
        for (int c0 = 0; c0 < 2; ++c0) {
            int c = tid + c0 * 256;
            int r = c >> 4, cc = c & 15;
            const float* vp = V + (size_t)(kb + r) * (NKV * HD) + kvh * HD + cc * 8;
            f32x4 a = *(const f32x4*)(vp);
            f32x4 b = *(const f32x4*)(vp + 4);
            #pragma unroll
            for (int j = 0; j < 4; ++j)
                VTs[(cc * 8 + j) * VT_STRIDE + r] = f2bf(a[j]);
            #pragma unroll
            for (int j = 0; j < 4; ++j)
                VTs[(cc * 8 + 4 + j) * VT_STRIDE + r] = f2bf(b[j]);
        }
        __syncthreads();   // staging visible

        // ---- QK^T: S[16 q][32 k] per wave ----
        f32x4 sc[2];
        sc[0] = (f32x4){0.f, 0.f, 0.f, 0.f};
        sc[1] = (f32x4){0.f, 0.f, 0.f, 0.f};
        #pragma unroll
        for (int d0 = 0; d0 < 4; ++d0) {
            #pragma unroll
            for (int nt = 0; nt < 2; ++nt) {
                bf16x8 kf = *(const bf16x8*)(&Ks[(nt * 16 + l16) * K_STRIDE + d0 * 32 + lq * 8]);
                sc[nt] = __builtin_amdgcn_mfma_f32_16x16x32_bf16(qf[d0], kf, sc[nt], 0, 0, 0);
            }
        }

        // ---- scale + ALiBi + causal mask + online softmax ----
        // C/D layout: reg i of lane -> row 4*lq + i, col l16 (per 16-col tile)
        float p[2][4];
        #pragma unroll
        for (int i = 0; i < 4; ++i) {
            const int qrow = qrow0 + 4 * lq + i;
            const int kc0 = kb + l16;
            const int kc1 = kb + 16 + l16;
            float v0 = sc[0][i] * QK_SCALE + slope * (float)(kc0 - qrow);
            float v1 = sc[1][i] * QK_SCALE + slope * (float)(kc1 - qrow);
            float s0 = (kc0 > qrow) ? -1e30f : v0;
            float s1 = (kc1 > qrow) ? -1e30f : v1;

            float rm = fmaxf(s0, s1);
            rm = fmaxf(rm, __shfl_xor(rm, 1));
            rm = fmaxf(rm, __shfl_xor(rm, 2));
            rm = fmaxf(rm, __shfl_xor(rm, 4));
            rm = fmaxf(rm, __shfl_xor(rm, 8));

            float mnew  = fmaxf(m_i[i], rm);
            float alpha = exp2f((m_i[i] - mnew) * LOG2E);
            m_i[i] = mnew;

            float p0 = exp2f((s0 - mnew) * LOG2E);
            float p1 = exp2f((s1 - mnew) * LOG2E);
            p[0][i] = p0;
            p[1][i] = p1;

            float ps = p0 + p1;
            ps += __shfl_xor(ps, 1);
            ps += __shfl_xor(ps, 2);
            ps += __shfl_xor(ps, 4);
            ps += __shfl_xor(ps, 8);
            l_i[i] = l_i[i] * alpha + ps;

            #pragma unroll
            for (int t = 0; t < 8; ++t) acc[t][i] *= alpha;
        }

        // ---- P (C-layout) -> LDS -> A-fragment layout ----
        short* PsW = &Ps[w][0];
        #pragma unroll
        for (int nt = 0; nt < 2; ++nt) {
            #pragma unroll
            for (int i = 0; i < 4; ++i)
                PsW[(4 * lq + i) * P_STRIDE + nt * 16 + l16] = f2bf(p[nt][i]);
        }
        asm volatile("s_waitcnt lgkmcnt(0)" ::: "memory");  // wave-local write->read
        bf16x8 pf = *(const bf16x8*)(&PsW[l16 * P_STRIDE + lq * 8]);

        // ---- PV: O[16 q][128 d] accumulate ----
        #pragma unroll
        for (int nt = 0; nt < 8; ++nt) {
            bf16x8 vf = *(const bf16x8*)(&VTs[(nt * 16 + l16) * VT_STRIDE + lq * 8]);
            acc[nt] = __builtin_amdgcn_mfma_f32_16x16x32_bf16(pf, vf, acc[nt], 0, 0, 0);
        }
    }

    // ---- epilogue: normalize and store fp32 ----
    #pragma unroll
    for (int i = 0; i < 4; ++i) {
        float rl = 1.0f / l_i[i];
        const size_t row = (size_t)(qrow0 + 4 * lq + i);
        float* op = O + row * (NHEADS * HD) + h * HD + l16;
        #pragma unroll
        for (int nt = 0; nt < 8; ++nt)
            op[nt * 16] = acc[nt][i] * rl;
    }
}

extern "C" void kernel_launch(void* const* d_in, const int* in_sizes, int n_in,
                              void* d_out, int out_size, void* d_ws, size_t ws_size,
                              hipStream_t stream) {
    const float* Q  = (const float*)d_in[0];
    const float* K  = (const float*)d_in[1];
    const float* V  = (const float*)d_in[2];
    const float* SL = (const float*)d_in[3];
    float* O = (float*)d_out;

    dim3 grid(NHEADS * NQT);   // 1024 blocks: (q-tile heavy-first) x heads
    dim3 block(256);           // 4 waves
    attn_fwd<<<grid, block, 0, stream>>>(Q, K, V, SL, O);
}

// Round 2
// 184.520 us; speedup vs baseline: 1.3109x; 1.3109x over previous
//
#include <hip/hip_runtime.h>
#include <hip/hip_bf16.h>

#define S_LEN 2048
#define NHEADS 32
#define NKV 8
#define HD 128
#define QK_SCALE 0.08838834764831845f   // 1/sqrt(128)
#define LOG2E 1.4426950408889634f

#define BQ 64                 // q rows per block
#define BK 32                 // kv rows per tile
#define NQT (S_LEN / BQ)      // 32 q tiles
#define QSTR (NHEADS * HD)    // 4096
#define KSTR (NKV * HD)       // 1024

#define K_STRIDE 136          // LDS row stride (shorts), 272B = 17*16 (b128-aligned, 2-way banks)
#define VT_STRIDE 40          // LDS row stride (shorts), 80B = 5*16  (b128-aligned, 2-way banks)
#define P_STRIDE 40

typedef __attribute__((ext_vector_type(8))) short bf16x8;
typedef __attribute__((ext_vector_type(4))) float f32x4;
typedef __attribute__((ext_vector_type(4))) unsigned u32x4;

__device__ inline unsigned cvt_pk_bf16(float lo, float hi) {
    unsigned r;
    asm("v_cvt_pk_bf16_f32 %0, %1, %2" : "=v"(r) : "v"(lo), "v"(hi));
    return r;
}
__device__ inline short f2bf(float f) {
    unsigned u = __float_as_uint(f);
    u += 0x7fffu + ((u >> 16) & 1u);
    return (short)(u >> 16);
}
__device__ inline bf16x8 as_bf16x8(u32x4 v) {
    union { u32x4 u; bf16x8 b; } c; c.u = v; return c.b;
}

__global__ __launch_bounds__(256) void attn_fwd(
    const float* __restrict__ Q, const float* __restrict__ K,
    const float* __restrict__ V, const float* __restrict__ SL,
    float* __restrict__ O)
{
    const int bx   = blockIdx.x;
    const int h    = bx & (NHEADS - 1);
    const int qt   = (NQT - 1) - (bx >> 5);     // heavy tiles dispatch first
    const int kvh  = h >> 2;
    const float slope = SL[h];

    const int tid  = threadIdx.x;
    const int w    = tid >> 6;
    const int lane = tid & 63;
    const int l16  = lane & 15;
    const int lq   = lane >> 4;

    __shared__ short Ks[BK * K_STRIDE];       // K tile row-major [k][d]
    __shared__ short VTs[HD * VT_STRIDE];     // V tile transposed [d][k]
    __shared__ short Ps[4][16 * P_STRIDE];    // per-wave P [q][k]

    const int qrow0 = qt * BQ + w * 16;

    // ---- Q fragments (A-operand: row=l16, k=8*lq+i), packed conversion ----
    bf16x8 qf[4];
    {
        const float* qp = Q + (size_t)(qrow0 + l16) * QSTR + h * HD + lq * 8;
        #pragma unroll
        for (int d0 = 0; d0 < 4; ++d0) {
            f32x4 a = *(const f32x4*)(qp + d0 * 32);
            f32x4 b = *(const f32x4*)(qp + d0 * 32 + 4);
            u32x4 t;
            t[0] = cvt_pk_bf16(a[0], a[1]); t[1] = cvt_pk_bf16(a[2], a[3]);
            t[2] = cvt_pk_bf16(b[0], b[1]); t[3] = cvt_pk_bf16(b[2], b[3]);
            qf[d0] = as_bf16x8(t);
        }
    }

    f32x4 acc[8];
    #pragma unroll
    for (int t = 0; t < 8; ++t) acc[t] = (f32x4){0.f, 0.f, 0.f, 0.f};
    float m_i[4] = {-1e30f, -1e30f, -1e30f, -1e30f};
    float l_i[4] = {0.f, 0.f, 0.f, 0.f};

    const int kv_end = qt * BQ + BQ;

    // ---- ALiBi far-tile skip: tiles with slope*(qrow_min - kb - 31) >= 45
    //      carry softmax weight <= e^-33 relative to the diagonal -> drop.
    int kb_start = 0;
    {
        float thresh = (float)(qt * BQ) - 31.0f - 45.0f / slope;
        int t = (int)floorf(thresh);
        kb_start = (t < 0) ? 0 : (((t >> 5) + 1) << 5);
    }

    // ---- staging thread mapping ----
    const int sr  = tid >> 4, scc = tid & 15;         // K: row sr(+16), 8 d per thread
    const int vd  = tid & 127, vrb = (tid >> 7) * 8;  // V: col d, 8 consecutive k per thread
    const float* Kbase = K + (size_t)kvh * HD + scc * 8;
    const float* Vbase = V + (size_t)kvh * HD + vd;

    float kr[2][8], vr[2][8];   // register prefetch buffers (static indexing only)

    auto load_regs = [&](int kb) {
        #pragma unroll
        for (int s = 0; s < 2; ++s) {
            const float* kp = Kbase + (size_t)(kb + sr + s * 16) * KSTR;
            *(f32x4*)&kr[s][0] = *(const f32x4*)kp;
            *(f32x4*)&kr[s][4] = *(const f32x4*)(kp + 4);
        }
        #pragma unroll
        for (int s = 0; s < 2; ++s)
            #pragma unroll
            for (int j = 0; j < 8; ++j)
                vr[s][j] = Vbase[(size_t)(kb + vrb + s * 16 + j) * KSTR];
    };

    auto store_tile = [&]() {
        #pragma unroll
        for (int s = 0; s < 2; ++s) {
            u32x4 t;
            t[0] = cvt_pk_bf16(kr[s][0], kr[s][1]);
            t[1] = cvt_pk_bf16(kr[s][2], kr[s][3]);
            t[2] = cvt_pk_bf16(kr[s][4], kr[s][5]);
            t[3] = cvt_pk_bf16(kr[s][6], kr[s][7]);
            *(u32x4*)&Ks[(sr + s * 16) * K_STRIDE + scc * 8] = t;
        }
        #pragma unroll
        for (int s = 0; s < 2; ++s) {
            u32x4 t;
            t[0] = cvt_pk_bf16(vr[s][0], vr[s][1]);
            t[1] = cvt_pk_bf16(vr[s][2], vr[s][3]);
            t[2] = cvt_pk_bf16(vr[s][4], vr[s][5]);
            t[3] = cvt_pk_bf16(vr[s][6], vr[s][7]);
            *(u32x4*)&VTs[vd * VT_STRIDE + vrb + s * 16] = t;   // contiguous k seg: 2-way banks
        }
    };

    load_regs(kb_start);

    for (int kb = kb_start; kb < kv_end; kb += BK) {
        __syncthreads();               // previous tile's LDS reads complete
        store_tile();
        __syncthreads();               // staging visible
        if (kb + BK < kv_end) load_regs(kb + BK);   // prefetch hides under compute

        // per-wave skip: fully causally-masked, or ALiBi-negligible for this wave
        const bool live = (kb <= qrow0 + 15) &&
                          (slope * (float)(qrow0 - kb - 31) < 45.0f);
        if (live) {
            // ---- QK^T ----
            f32x4 sc0 = (f32x4){0.f,0.f,0.f,0.f};
            f32x4 sc1 = (f32x4){0.f,0.f,0.f,0.f};
            #pragma unroll
            for (int d0 = 0; d0 < 4; ++d0) {
                bf16x8 kf0 = *(const bf16x8*)&Ks[l16 * K_STRIDE + d0 * 32 + lq * 8];
                bf16x8 kf1 = *(const bf16x8*)&Ks[(16 + l16) * K_STRIDE + d0 * 32 + lq * 8];
                sc0 = __builtin_amdgcn_mfma_f32_16x16x32_bf16(qf[d0], kf0, sc0, 0, 0, 0);
                sc1 = __builtin_amdgcn_mfma_f32_16x16x32_bf16(qf[d0], kf1, sc1, 0, 0, 0);
            }

            // ---- scale + ALiBi + causal + online softmax (defer-max THR=8) ----
            float p0v[4], p1v[4];
            #pragma unroll
            for (int i = 0; i < 4; ++i) {
                const int qrow = qrow0 + 4 * lq + i;
                const int kc0 = kb + l16;
                const int kc1 = kb + 16 + l16;
                float s0 = (kc0 > qrow) ? -1e30f
                         : sc0[i] * QK_SCALE + slope * (float)(kc0 - qrow);
                float s1 = (kc1 > qrow) ? -1e30f
                         : sc1[i] * QK_SCALE + slope * (float)(kc1 - qrow);

                float rm = fmaxf(s0, s1);
                rm = fmaxf(rm, __shfl_xor(rm, 1));
                rm = fmaxf(rm, __shfl_xor(rm, 2));
                rm = fmaxf(rm, __shfl_xor(rm, 4));
                rm = fmaxf(rm, __shfl_xor(rm, 8));

                if (rm > m_i[i] + 8.0f) {       // defer-max: rescale only on real growth
                    float alpha = exp2f((m_i[i] - rm) * LOG2E);
                    m_i[i] = rm;
                    l_i[i] *= alpha;
                    #pragma unroll
                    for (int t = 0; t < 8; ++t) acc[t][i] *= alpha;
                }
                float p0 = exp2f((s0 - m_i[i]) * LOG2E);
                float p1 = exp2f((s1 - m_i[i]) * LOG2E);
                p0v[i] = p0; p1v[i] = p1;

                float ps = p0 + p1;
                ps += __shfl_xor(ps, 1);
                ps += __shfl_xor(ps, 2);
                ps += __shfl_xor(ps, 4);
                ps += __shfl_xor(ps, 8);
                l_i[i] += ps;
            }

            // ---- P (C-layout) -> LDS -> A-fragment ----
            short* PsW = &Ps[w][0];
            #pragma unroll
            for (int i = 0; i < 4; ++i) {
                PsW[(4 * lq + i) * P_STRIDE + l16]      = f2bf(p0v[i]);
                PsW[(4 * lq + i) * P_STRIDE + 16 + l16] = f2bf(p1v[i]);
            }
            asm volatile("s_waitcnt lgkmcnt(0)" ::: "memory");
            bf16x8 pf = *(const bf16x8*)&PsW[l16 * P_STRIDE + lq * 8];

            // ---- PV ----
            #pragma unroll
            for (int nt = 0; nt < 8; ++nt) {
                bf16x8 vf = *(const bf16x8*)&VTs[(nt * 16 + l16) * VT_STRIDE + lq * 8];
                acc[nt] = __builtin_amdgcn_mfma_f32_16x16x32_bf16(pf, vf, acc[nt], 0, 0, 0);
            }
        }
    }

    // ---- epilogue ----
    #pragma unroll
    for (int i = 0; i < 4; ++i) {
        float rl = 1.0f / l_i[i];
        const size_t row = (size_t)(qrow0 + 4 * lq + i);
        float* op = O + row * QSTR + h * HD + l16;
        #pragma unroll
        for (int nt = 0; nt < 8; ++nt)
            op[nt * 16] = acc[nt][i] * rl;
    }
}

extern "C" void kernel_launch(void* const* d_in, const int* in_sizes, int n_in,
                              void* d_out, int out_size, void* d_ws, size_t ws_size,
                              hipStream_t stream) {
    const float* Q  = (const float*)d_in[0];
    const float* K  = (const float*)d_in[1];
    const float* V  = (const float*)d_in[2];
    const float* SL = (const float*)d_in[3];
    float* O = (float*)d_out;

    dim3 grid(NHEADS * NQT);
    dim3 block(256);
    attn_fwd<<<grid, block, 0, stream>>>(Q, K, V, SL, O);
}